// Round 8
// baseline (298.944 us; speedup 1.0000x reference)
//
#include <hip/hip_runtime.h>
#include <hip/hip_bf16.h>
#include <math.h>

#define D_MODEL 768
#define NTOK    8192   // B*N
#define SEQ     1024
#define NH      12
#define DHD     64
#define DFF     3072

typedef __attribute__((ext_vector_type(8)))  __bf16 bf16x8;
typedef __attribute__((ext_vector_type(4)))  float  f32x4;
typedef __attribute__((ext_vector_type(16))) float  f32x16;
typedef __attribute__((ext_vector_type(4)))  unsigned short us4;

typedef const __attribute__((address_space(1))) void g_void;
typedef __attribute__((address_space(3))) void lds_void;

__device__ __forceinline__ unsigned short f2bf(float f) {
  unsigned u = __float_as_uint(f);
  u += 0x7fffu + ((u >> 16) & 1u);   // RNE to bf16
  return (unsigned short)(u >> 16);
}

__device__ __forceinline__ f32x4 mfma16(bf16x8 a, bf16x8 b, f32x4 c) {
  return __builtin_amdgcn_mfma_f32_16x16x32_bf16(a, b, c, 0, 0, 0);
}
__device__ __forceinline__ f32x16 mfma32(bf16x8 a, bf16x8 b, f32x16 c) {
  return __builtin_amdgcn_mfma_f32_32x32x16_bf16(a, b, c, 0, 0, 0);
}

// async global->LDS, 16B per lane; LDS dest = uniform base + lane*16
__device__ __forceinline__ void gload_lds16(const unsigned short* g, unsigned short* l) {
  __builtin_amdgcn_global_load_lds((g_void*)g, (lds_void*)l, 16, 0, 0);
}

// v_permlane32_swap_b32: a[32..63] <-> b[0..31] (both operands updated)
__device__ __forceinline__ void plswap(unsigned &a, unsigned &b) {
  asm("v_permlane32_swap_b32 %0, %1" : "+v"(a), "+v"(b));
}
__device__ __forceinline__ bf16x8 mk8(unsigned a, unsigned b, unsigned c, unsigned d) {
  union { unsigned u[4]; bf16x8 v; } t;
  t.u[0] = a; t.u[1] = b; t.u[2] = c; t.u[3] = d;
  return t.v;
}

// ---------------- LayerNorm: one wave per row of 768, fp32 in -> bf16 out ----
__global__ __launch_bounds__(256)
void ln_kernel(const float* __restrict__ x, const float* __restrict__ gam,
               const float* __restrict__ bet, unsigned short* __restrict__ out) {
  const int w = threadIdx.x >> 6, lane = threadIdx.x & 63;
  const size_t row = (size_t)blockIdx.x * 4 + w;
  const float* xr = x + row * D_MODEL;
  f32x4 v[3];
#pragma unroll
  for (int c = 0; c < 3; ++c) v[c] = *(const f32x4*)(xr + c * 256 + lane * 4);
  float s = 0.f;
#pragma unroll
  for (int c = 0; c < 3; ++c)
#pragma unroll
    for (int j = 0; j < 4; ++j) s += v[c][j];
#pragma unroll
  for (int o = 32; o; o >>= 1) s += __shfl_xor(s, o);
  const float mu = s * (1.0f / D_MODEL);
  float vs = 0.f;
#pragma unroll
  for (int c = 0; c < 3; ++c)
#pragma unroll
    for (int j = 0; j < 4; ++j) { float d = v[c][j] - mu; vs += d * d; }
#pragma unroll
  for (int o = 32; o; o >>= 1) vs += __shfl_xor(vs, o);
  const float rs = rsqrtf(vs * (1.0f / D_MODEL) + 1e-5f);
  unsigned short* orow = out + row * D_MODEL;
#pragma unroll
  for (int c = 0; c < 3; ++c) {
    us4 o4;
#pragma unroll
    for (int j = 0; j < 4; ++j) {
      int idx = c * 256 + lane * 4 + j;
      o4[j] = f2bf((v[c][j] - mu) * rs * gam[idx] + bet[idx]);
    }
    *(us4*)(orow + c * 256 + lane * 4) = o4;
  }
}

// ------------- weight transpose + cast: W[K][Nc] f32 -> Wt[Nc][K] bf16 -------
__global__ __launch_bounds__(256)
void wtrans_kernel(const float* __restrict__ W, unsigned short* __restrict__ Wt,
                   int K, int Nc) {
  __shared__ float t[32][33];
  const int tx = threadIdx.x & 31, ty = threadIdx.x >> 5;  // 32x8
  const int nb = blockIdx.x * 32, kb = blockIdx.y * 32;
#pragma unroll
  for (int i = 0; i < 4; ++i)
    t[ty + 8 * i][tx] = W[(size_t)(kb + ty + 8 * i) * Nc + nb + tx];
  __syncthreads();
#pragma unroll
  for (int i = 0; i < 4; ++i)
    Wt[(size_t)(nb + ty + 8 * i) * K + kb + tx] = f2bf(t[tx][ty + 8 * i]);
}

// ------ bias reshape: rel[H][N][N] f32 -> biasF bf16 in S^T-fragment order,
// PRE-SCALED by log2(e) (softmax runs in log2 domain). Lane l: q = qt*32+(l&31);
// reg r: k = kt*32 + (r&3) + 8*(r>>2) + 4*(l>>5). Packed (r0,r1)(r2,r3)..
__global__ __launch_bounds__(256)
void brelayout_kernel(const float* __restrict__ rel, unsigned short* __restrict__ bF) {
  const int gw = blockIdx.x * 4 + (threadIdx.x >> 6);  // (h*32+qt)*32+ktg
  const int lane = threadIdx.x & 63;
  const int ktg = gw & 31, qt = (gw >> 5) & 31, h = gw >> 10;
  const int q = qt * 32 + (lane & 31), hi = lane >> 5;
  const float* src = rel + ((size_t)h * SEQ + q) * SEQ + ktg * 32 + 4 * hi;
  const float L2E = 1.4426950408889634f;
  unsigned ow[8];
#pragma unroll
  for (int g = 0; g < 4; ++g) {
    f32x4 v = *(const f32x4*)(src + g * 8);
    asm("v_cvt_pk_bf16_f32 %0, %1, %2" : "=v"(ow[2 * g])     : "v"(v[0] * L2E), "v"(v[1] * L2E));
    asm("v_cvt_pk_bf16_f32 %0, %1, %2" : "=v"(ow[2 * g + 1]) : "v"(v[2] * L2E), "v"(v[3] * L2E));
  }
  unsigned short* dst = bF + (((size_t)gw) * 64 + lane) * 16;
  *(uint4*)(dst)     = make_uint4(ow[0], ow[1], ow[2], ow[3]);
  *(uint4*)(dst + 8) = make_uint4(ow[4], ow[5], ow[6], ow[7]);
}

// -------- GEMM: C[M][N] = A[M][K] @ Bt[N][K]^T, bf16, fused epilogue --------
// 128x128 tile, BK=32, 4 waves (wave tile 64x64 = 2x2 of 32x32x16 MFMA).
// Counted-vmcnt pipeline (depth 2, 3 LDS buffers): raw s_barrier + vmcnt(4)
// keeps the newest stage's loads in flight ACROSS the barrier (no full drain).
// LDS XOR-swizzle (unit ^= row&3 on 16B units within 64B rows) applied on the
// per-lane GLOBAL source (gload dest linear) and on the ds_read col.
#define MODE_QKV  0
#define MODE_PROJ 1
#define MODE_FFN1 2
#define MODE_FFN2 3

template <int MODE>
__global__ __launch_bounds__(256, 3)
void gemm_bt(const unsigned short* __restrict__ A, const unsigned short* __restrict__ Bt,
             int K, const float* __restrict__ bias, const float* __restrict__ resid,
             float* __restrict__ outF, unsigned short* __restrict__ o0,
             unsigned short* __restrict__ o1, unsigned short* __restrict__ o2) {
  __shared__ alignas(16) unsigned short smem[2][3][128 * 32];  // [A/B][buf][tile] 48KB
  const int tid = threadIdx.x;
  const int w = tid >> 6, lane = tid & 63;
  const int l31 = lane & 31, hi = lane >> 5;
  const int wm = w >> 1, wn = w & 1;
  // XCD-chunked bijective swizzle (all grids are multiples of 8 blocks)
  const int nwg = gridDim.x * gridDim.y;
  const int bid0 = blockIdx.y * gridDim.x + blockIdx.x;
  const int cpx = nwg >> 3;
  const int bid = (bid0 & 7) * cpx + (bid0 >> 3);
  const int bx = bid % gridDim.x, by = bid / gridDim.x;
  const size_t m0 = (size_t)by * 128;
  const size_t n0 = (size_t)bx * 128;
  const unsigned short* gA = A + m0 * K;
  const unsigned short* gB = Bt + n0 * K;

  // staging decomposition: lane -> (row-in-16-group, 16B unit), source col XOR'd
  const int r16 = lane >> 2;          // 0..15
  const int u4 = lane & 3;            // 16B unit within 64B row
  const int ucol = (u4 ^ (r16 & 3)) * 8;  // swizzled element offset in BK=32 row

  f32x16 acc[2][2];
#pragma unroll
  for (int i = 0; i < 2; ++i)
#pragma unroll
    for (int j = 0; j < 2; ++j) acc[i][j] = (f32x16)(0.f);
  const int nk = K >> 5;   // nk >= 24 for all our shapes

  // one stage = 4 gload_lds per wave (2 A + 2 B) -> vmcnt granularity 4
  auto stage = [&](int buf, int kt) {
#pragma unroll
    for (int g = 0; g < 2; ++g) {
      const int rowb = w * 32 + g * 16;  // wave-uniform base row (multiple of 16)
      gload_lds16(gA + (size_t)(rowb + r16) * K + kt * 32 + ucol, &smem[0][buf][rowb * 32]);
      gload_lds16(gB + (size_t)(rowb + r16) * K + kt * 32 + ucol, &smem[1][buf][rowb * 32]);
    }
  };

  // frag read offsets: row = base + l31 (base % 32 == 0), unit j = ks*2 + hi
  const int swr = l31 & 3;
  const int rA = (wm * 64 + l31) * 32;
  const int rB = (wn * 64 + l31) * 32;

  // prologue: two stages in flight; wait for the first, keep the second flying
  stage(0, 0);
  stage(1, 1);
  asm volatile("s_waitcnt vmcnt(4)" ::: "memory");
  __builtin_amdgcn_s_barrier();

  int bcur = 0;
  for (int kt = 0; kt < nk; ++kt) {
    const int bpre = (bcur == 0) ? 2 : bcur - 1;   // (kt+2)%3
    if (kt + 2 < nk) stage(bpre, kt + 2);
    bf16x8 af[2][2], bf[2][2];
#pragma unroll
    for (int mt = 0; mt < 2; ++mt)
#pragma unroll
      for (int ks = 0; ks < 2; ++ks) {
        af[mt][ks] = *(const bf16x8*)&smem[0][bcur][rA + mt * 1024 + (((ks * 2 + hi) ^ swr) * 8)];
        bf[mt][ks] = *(const bf16x8*)&smem[1][bcur][rB + mt * 1024 + (((ks * 2 + hi) ^ swr) * 8)];
      }
    __builtin_amdgcn_s_setprio(1);
#pragma unroll
    for (int mt = 0; mt < 2; ++mt)
#pragma unroll
      for (int nt = 0; nt < 2; ++nt)
#pragma unroll
        for (int ks = 0; ks < 2; ++ks)
          acc[mt][nt] = mfma32(af[mt][ks], bf[nt][ks], acc[mt][nt]);
    __builtin_amdgcn_s_setprio(0);
    // wait only for the NEXT tile's stage (oldest 4); newest stage stays in flight
    if (kt + 2 < nk) asm volatile("s_waitcnt vmcnt(4)" ::: "memory");
    else             asm volatile("s_waitcnt vmcnt(0)" ::: "memory");
    __builtin_amdgcn_s_barrier();
    bcur = (bcur == 2) ? 0 : bcur + 1;
  }

  // ---- V-region of QKV: transpose through (now dead) LDS, coalesced stores
  if constexpr (MODE == MODE_QKV) {
    if (bx >= 12) {
      unsigned short* tb = &smem[0][0][0];  // [128 n][136 m] (pad: 16B rows, banks ok)
#pragma unroll
      for (int mt = 0; mt < 2; ++mt)
#pragma unroll
        for (int nt = 0; nt < 2; ++nt)
#pragma unroll
          for (int r = 0; r < 16; ++r) {
            const int nl = wn * 64 + nt * 32 + l31;
            const int ml = wm * 64 + mt * 32 + (r & 3) + 8 * (r >> 2) + 4 * hi;
            tb[nl * 136 + ml] = f2bf(acc[mt][nt][r] + bias[(int)n0 + nl]);
          }
      __syncthreads();
      const int rr = tid & 127, half = tid >> 7;
      const int n2 = ((int)n0 - 1536) + rr;
      const int hh = n2 >> 6, dh = n2 & 63;
      const int b2 = (int)(m0 >> 10), nq0 = (int)(m0 & 1023);
      unsigned short* dst = o2 + ((size_t)(b2 * NH + hh) * DHD + dh) * SEQ + nq0 + half * 64;
      const unsigned short* src = tb + rr * 136 + half * 64;
#pragma unroll
      for (int i = 0; i < 4; ++i)
        *(uint4*)(dst + i * 8) = *(const uint4*)(src + i * 8);
      return;
    }
  }

  // epilogue: 32x32 C/D map: n = tile + l31, m = tile + (r&3) + 8*(r>>2) + 4*hi
#pragma unroll
  for (int mt = 0; mt < 2; ++mt) {
#pragma unroll
    for (int nt = 0; nt < 2; ++nt) {
#pragma unroll
      for (int r = 0; r < 16; ++r) {
        const int m = (int)m0 + wm * 64 + mt * 32 + (r & 3) + 8 * (r >> 2) + 4 * hi;
        const int n = (int)n0 + wn * 64 + nt * 32 + l31;
        float v = acc[mt][nt][r] + bias[n];
        if constexpr (MODE == MODE_QKV) {
          const int b = m >> 10, nq = m & 1023;
          if (n < 768) {
            // Q: pre-scale by 0.125*log2(e) (softmax runs in log2 domain)
            const int h = n >> 6, dh = n & 63;
            o0[(((size_t)(b * NH + h)) * SEQ + nq) * DHD + dh] =
                f2bf(v * 0.1803368801111244f);
          } else {
            const int n2 = n - 768, h = n2 >> 6, dh = n2 & 63;
            o1[(((size_t)(b * NH + h)) * SEQ + nq) * DHD + dh] = f2bf(v);
          }
        } else if constexpr (MODE == MODE_PROJ) {
          const size_t off = (size_t)m * D_MODEL + n;
          outF[off] = v + resid[off];
        } else if constexpr (MODE == MODE_FFN1) {
          // gelu(v) = 0.5v(1+tanh(u)) == v * sigmoid(2u), u=0.79788456(v+0.044715v^3)
          const float e = __expf(-1.5957691216057308f * (v + 0.044715f * v * v * v));
          o0[(size_t)m * DFF + n] = f2bf(v / (1.0f + e));
        } else {  // FFN2: in-place residual on outF (x2 lives there)
          const size_t off = (size_t)m * D_MODEL + n;
          outF[off] = v + resid[off];
        }
      }
    }
  }
}

// ------- fused flash attention: 4 waves x 32 q-rows, 32x32x16 MFMA ----------
// K/V staged into LDS in fragment order (shared by all 4 waves); swapped
// operands: S^T[k][q] = mfma(K,Q) so q = lane&31, k = reg-mapped. Softmax in
// log2 domain (Q pre-scaled, biasF pre-scaled, exp2), fully in-lane with
// defer-max. P -> PV B-frags entirely in-register via cvt_pk + permlane32_swap.
__global__ __launch_bounds__(256, 4)
void attn_kernel(const unsigned short* __restrict__ q, const unsigned short* __restrict__ k,
                 const unsigned short* __restrict__ vt, const unsigned short* __restrict__ bF,
                 unsigned short* __restrict__ ctx) {
  // kv slots: [buf][slot 0..15][64 lanes * 8 shorts]; slots 0-7 = K (kt*4+ds),
  // slots 8-15 = V (8 + dt*4 + kh). Each slot = one ds_read_b128 fragment set.
  __shared__ alignas(16) unsigned short kv[2][16][64 * 8];
  const int tid = threadIdx.x, w = tid >> 6, lane = tid & 63;
  const int l31 = lane & 31, hi = lane >> 5;
  // XCD-chunked swizzle (768 % 8 == 0 -> bijective): 12 bh per XCD, K/V L2-res.
  const int bid = (blockIdx.x & 7) * 96 + (blockIdx.x >> 3);
  const int bh = bid >> 3, qblk = bid & 7;
  const int b = bh / NH, h = bh % NH;
  const int q0w = qblk * 128 + w * 32;
  const unsigned short* qp = q + (size_t)bh * SEQ * DHD;
  const unsigned short* kp = k + (size_t)bh * SEQ * DHD;
  const unsigned short* vp = vt + (size_t)bh * DHD * SEQ;
  // bias fragment stream for this wave's 32 q-rows (qt = qblk*4 + w)
  const unsigned short* bfp = bF + ((((size_t)(h * 32 + qblk * 4 + w)) * 32) * 64 + lane) * 16;

  // Q B-fragments (kept all kernel): col q = l31, d = ds*16 + hi*8 + e
  bf16x8 Qf[4];
#pragma unroll
  for (int ds = 0; ds < 4; ++ds)
    Qf[ds] = *(const bf16x8*)(qp + (size_t)(q0w + l31) * DHD + ds * 16 + hi * 8);

  f32x16 o[2];
#pragma unroll
  for (int dt = 0; dt < 2; ++dt) o[dt] = (f32x16)(0.f);
  float mrun = -INFINITY, lrun = 0.f;  // log2-domain running max / sum

  auto stage = [&](int buf, int kb) {
    if (w < 2) {  // K slots: kt = w, ds 0..3; lane = A-frag row k, cols d
      const unsigned short* g0 = kp + (size_t)(kb * 64 + w * 32 + l31) * DHD + hi * 8;
#pragma unroll
      for (int ds = 0; ds < 4; ++ds)
        gload_lds16(g0 + ds * 16, &kv[buf][w * 4 + ds][0]);
    } else {      // V slots: dt = w-2, kh 0..3; lane = A-frag row d, cols k
      const int dt = w - 2;
      const unsigned short* g0 = vp + (size_t)(dt * 32 + l31) * SEQ + kb * 64 + hi * 8;
#pragma unroll
      for (int kh = 0; kh < 4; ++kh)
        gload_lds16(g0 + kh * 16, &kv[buf][8 + dt * 4 + kh][0]);
    }
  };

  stage(0, 0);
  __syncthreads();
  for (int kb = 0; kb < SEQ / 64; ++kb) {
    const int buf = kb & 1;
    if (kb + 1 < SEQ / 64) stage(buf ^ 1, kb + 1);

    // ---- S^T for 64 keys: 2 kt-tiles x 4 d-slices
    f32x16 s0 = (f32x16)(0.f), s1 = (f32x16)(0.f);
    __builtin_amdgcn_s_setprio(1);
#pragma unroll
    for (int ds = 0; ds < 4; ++ds) {
      bf16x8 kf0 = *(const bf16x8*)&kv[buf][ds][lane * 8];
      s0 = mfma32(kf0, Qf[ds], s0);
      bf16x8 kf1 = *(const bf16x8*)&kv[buf][4 + ds][lane * 8];
      s1 = mfma32(kf1, Qf[ds], s1);
    }
    __builtin_amdgcn_s_setprio(0);

    // ---- bias add (bf16 fragment stream, log2 domain; Q already scaled)
    const unsigned short* bb = bfp + (size_t)(kb * 2) * 64 * 16;
    uint4 a0 = *(const uint4*)(bb),            a1 = *(const uint4*)(bb + 8);
    uint4 c0 = *(const uint4*)(bb + 64 * 16),  c1 = *(const uint4*)(bb + 64 * 16 + 8);
    unsigned uw0[8] = {a0.x, a0.y, a0.z, a0.w, a1.x, a1.y, a1.z, a1.w};
    unsigned uw1[8] = {c0.x, c0.y, c0.z, c0.w, c1.x, c1.y, c1.z, c1.w};
    float p0[16], p1[16];
#pragma unroll
    for (int j = 0; j < 8; ++j) {
      p0[2 * j]     = s0[2 * j]     + __uint_as_float(uw0[j] << 16);
      p0[2 * j + 1] = s0[2 * j + 1] + __uint_as_float(uw0[j] & 0xffff0000u);
      p1[2 * j]     = s1[2 * j]     + __uint_as_float(uw1[j] << 16);
      p1[2 * j + 1] = s1[2 * j + 1] + __uint_as_float(uw1[j] & 0xffff0000u);
    }

    // ---- softmax (defer-max, log2 domain): THR = 11 (~= 7.6 nats)
    float pmax = p0[0];
#pragma unroll
    for (int i = 1; i < 16; ++i) pmax = fmaxf(pmax, p0[i]);
#pragma unroll
    for (int i = 0; i < 16; ++i) pmax = fmaxf(pmax, p1[i]);
    if (!__all(pmax - mrun <= 11.0f)) {
      float pm = fmaxf(pmax, __shfl_xor(pmax, 32));
      const float mn = fmaxf(mrun, pm);
      const float al = __builtin_amdgcn_exp2f(mrun - mn);
      mrun = mn;
      lrun *= al;
#pragma unroll
      for (int dt = 0; dt < 2; ++dt)
#pragma unroll
        for (int r = 0; r < 16; ++r) o[dt][r] *= al;
    }
#pragma unroll
    for (int i = 0; i < 16; ++i) { p0[i] = __builtin_amdgcn_exp2f(p0[i] - mrun); lrun += p0[i]; }
#pragma unroll
    for (int i = 0; i < 16; ++i) { p1[i] = __builtin_amdgcn_exp2f(p1[i] - mrun); lrun += p1[i]; }

    // ---- pack P -> bf16 pairs; permlane32_swap assembles PV B-frags in-reg.
    unsigned wpk[16];
#pragma unroll
    for (int i = 0; i < 8; ++i) {
      asm("v_cvt_pk_bf16_f32 %0, %1, %2" : "=v"(wpk[i])     : "v"(p0[2 * i]), "v"(p0[2 * i + 1]));
      asm("v_cvt_pk_bf16_f32 %0, %1, %2" : "=v"(wpk[8 + i]) : "v"(p1[2 * i]), "v"(p1[2 * i + 1]));
    }
    plswap(wpk[0], wpk[2]);   plswap(wpk[1], wpk[3]);
    plswap(wpk[4], wpk[6]);   plswap(wpk[5], wpk[7]);
    plswap(wpk[8], wpk[10]);  plswap(wpk[9], wpk[11]);
    plswap(wpk[12], wpk[14]); plswap(wpk[13], wpk[15]);
    bf16x8 pf[4];
    pf[0] = mk8(wpk[0], wpk[1], wpk[2], wpk[3]);
    pf[1] = mk8(wpk[4], wpk[5], wpk[6], wpk[7]);
    pf[2] = mk8(wpk[8], wpk[9], wpk[10], wpk[11]);
    pf[3] = mk8(wpk[12], wpk[13], wpk[14], wpk[15]);

    // ---- PV: O^T[d][q] += V^T-frag x P-frag
    __builtin_amdgcn_s_setprio(1);
#pragma unroll
    for (int dt = 0; dt < 2; ++dt)
#pragma unroll
      for (int kh = 0; kh < 4; ++kh) {
        bf16x8 vf = *(const bf16x8*)&kv[buf][8 + dt * 4 + kh][lane * 8];
        o[dt] = mfma32(vf, pf[kh], o[dt]);
      }
    __builtin_amdgcn_s_setprio(0);

    __syncthreads();  // staging of buf^1 complete + all waves done with buf
  }

  lrun += __shfl_xor(lrun, 32);
  const float inv = 1.0f / lrun;
  // O^T reg r: d = dt*32 + (r&3) + 8*(r>>2) + 4*hi, q = l31
  unsigned short* crow = ctx + ((size_t)b * SEQ + q0w + l31) * D_MODEL + h * DHD;
#pragma unroll
  for (int dt = 0; dt < 2; ++dt)
#pragma unroll
    for (int g = 0; g < 4; ++g) {
      us4 ov;
#pragma unroll
      for (int j = 0; j < 4; ++j) ov[j] = f2bf(o[dt][4 * g + j] * inv);
      *(us4*)(crow + dt * 32 + g * 8 + 4 * hi) = ov;
    }
}

// ----------------------------------------------------------------------------
extern "C" void kernel_launch(void* const* d_in, const int* in_sizes, int n_in,
                              void* d_out, int out_size, void* d_ws, size_t ws_size,
                              hipStream_t stream) {
  (void)in_sizes; (void)n_in; (void)out_size; (void)ws_size;
  const float* x     = (const float*)d_in[0];
  const float* ln1_g = (const float*)d_in[1];
  const float* ln1_b = (const float*)d_in[2];
  const float* wqkv  = (const float*)d_in[3];
  const float* bqkv  = (const float*)d_in[4];
  const float* wo    = (const float*)d_in[5];
  const float* bo    = (const float*)d_in[6];
  const float* rel   = (const float*)d_in[7];
  const float* ln2_g = (const float*)d_in[8];
  const float* ln2_b = (const float*)d_in[9];
  const float* w1    = (const float*)d_in[10];
  const float* b1    = (const float*)d_in[11];
  const float* w2    = (const float*)d_in[12];
  const float* b2    = (const float*)d_in[13];
  float* out = (float*)d_out;

  char* p = (char*)d_ws;
  auto take = [&](size_t bytes) {
    void* r = (void*)p;
    p += (bytes + 255) & ~(size_t)255;
    return r;
  };
  unsigned short* hbuf  = (unsigned short*)take((size_t)NTOK * D_MODEL * 2);
  unsigned short* wqkvT = (unsigned short*)take((size_t)2304 * 768 * 2);
  unsigned short* woT   = (unsigned short*)take((size_t)768 * 768 * 2);
  unsigned short* w1T   = (unsigned short*)take((size_t)3072 * 768 * 2);
  unsigned short* w2T   = (unsigned short*)take((size_t)768 * 3072 * 2);
  unsigned short* qbuf  = (unsigned short*)take((size_t)8 * NH * SEQ * DHD * 2);
  unsigned short* kbuf  = (unsigned short*)take((size_t)8 * NH * SEQ * DHD * 2);
  unsigned short* vtbuf = (unsigned short*)take((size_t)8 * NH * SEQ * DHD * 2);
  unsigned short* ctxb  = (unsigned short*)take((size_t)NTOK * D_MODEL * 2);
  unsigned short* h1buf = (unsigned short*)take((size_t)NTOK * DFF * 2);
  // biasF (25.2 MB) aliases h1buf (50.3 MB): dead before FFN1 writes h1buf.
  unsigned short* biasF = h1buf;
  // x2 (post-attention residual stream) lives in d_out (fp32).

  // weight prep (independent of activations)
  wtrans_kernel<<<dim3(2304 / 32, 768 / 32), 256, 0, stream>>>(wqkv, wqkvT, 768, 2304);
  wtrans_kernel<<<dim3(768 / 32, 768 / 32), 256, 0, stream>>>(wo, woT, 768, 768);
  wtrans_kernel<<<dim3(3072 / 32, 768 / 32), 256, 0, stream>>>(w1, w1T, 768, 3072);
  wtrans_kernel<<<dim3(768 / 32, 3072 / 32), 256, 0, stream>>>(w2, w2T, 3072, 768);
  // bias -> bf16 fragment order (pre-scaled by log2 e)
  brelayout_kernel<<<NH * 32 * 32 / 4, 256, 0, stream>>>(rel, biasF);

  // LN1: x -> h (bf16)
  ln_kernel<<<NTOK / 4, 256, 0, stream>>>(x, ln1_g, ln1_b, hbuf);
  // QKV: h @ wqkv + bqkv -> q (pre-scaled), k, Vt (bf16, attention layouts)
  gemm_bt<MODE_QKV><<<dim3(2304 / 128, NTOK / 128), 256, 0, stream>>>(
      hbuf, wqkvT, 768, bqkv, nullptr, nullptr, qbuf, kbuf, vtbuf);
  // attention -> ctx (bf16, [tok][D])
  attn_kernel<<<8 * NH * (SEQ / 128), 256, 0, stream>>>(qbuf, kbuf, vtbuf, biasF, ctxb);
  // proj: ctx @ wo + bo + x -> x2 (fp32, in d_out)
  gemm_bt<MODE_PROJ><<<dim3(768 / 128, NTOK / 128), 256, 0, stream>>>(
      ctxb, woT, 768, bo, x, out, nullptr, nullptr, nullptr);
  // LN2: x2 -> h2 (bf16, reuse hbuf)
  ln_kernel<<<NTOK / 4, 256, 0, stream>>>(out, ln2_g, ln2_b, hbuf);
  // FFN1: h2 @ w1 + b1, gelu -> h1 (bf16)
  gemm_bt<MODE_FFN1><<<dim3(DFF / 128, NTOK / 128), 256, 0, stream>>>(
      hbuf, w1T, 768, b1, nullptr, nullptr, h1buf, nullptr, nullptr);
  // FFN2: h1 @ w2 + b2 + x2 -> out (fp32, in place on d_out)
  gemm_bt<MODE_FFN2><<<dim3(768 / 128, NTOK / 128), 256, 0, stream>>>(
      h1buf, w2T, 3072, b2, out, out, nullptr, nullptr, nullptr);
}

// Round 9
// 281.531 us; speedup vs baseline: 1.0618x; 1.0618x over previous
//
#include <hip/hip_runtime.h>
#include <hip/hip_bf16.h>
#include <math.h>

#define D_MODEL 768
#define NTOK    8192   // B*N
#define SEQ     1024
#define NH      12
#define DHD     64
#define DFF     3072

typedef __attribute__((ext_vector_type(8)))  __bf16 bf16x8;
typedef __attribute__((ext_vector_type(4)))  float  f32x4;
typedef __attribute__((ext_vector_type(16))) float  f32x16;
typedef __attribute__((ext_vector_type(4)))  unsigned short us4;

typedef const __attribute__((address_space(1))) void g_void;
typedef __attribute__((address_space(3))) void lds_void;

__device__ __forceinline__ unsigned short f2bf(float f) {
  unsigned u = __float_as_uint(f);
  u += 0x7fffu + ((u >> 16) & 1u);   // RNE to bf16
  return (unsigned short)(u >> 16);
}

__device__ __forceinline__ f32x16 mfma32(bf16x8 a, bf16x8 b, f32x16 c) {
  return __builtin_amdgcn_mfma_f32_32x32x16_bf16(a, b, c, 0, 0, 0);
}

// async global->LDS, 16B per lane; LDS dest = uniform base + lane*16
__device__ __forceinline__ void gload_lds16(const unsigned short* g, unsigned short* l) {
  __builtin_amdgcn_global_load_lds((g_void*)g, (lds_void*)l, 16, 0, 0);
}

// v_permlane32_swap_b32: a[32..63] <-> b[0..31] (both operands updated)
__device__ __forceinline__ void plswap(unsigned &a, unsigned &b) {
  asm("v_permlane32_swap_b32 %0, %1" : "+v"(a), "+v"(b));
}
__device__ __forceinline__ bf16x8 mk8(unsigned a, unsigned b, unsigned c, unsigned d) {
  union { unsigned u[4]; bf16x8 v; } t;
  t.u[0] = a; t.u[1] = b; t.u[2] = c; t.u[3] = d;
  return t.v;
}

// ---------------- LayerNorm: one wave per row of 768, fp32 in -> bf16 out ----
__global__ __launch_bounds__(256)
void ln_kernel(const float* __restrict__ x, const float* __restrict__ gam,
               const float* __restrict__ bet, unsigned short* __restrict__ out) {
  const int w = threadIdx.x >> 6, lane = threadIdx.x & 63;
  const size_t row = (size_t)blockIdx.x * 4 + w;
  const float* xr = x + row * D_MODEL;
  f32x4 v[3];
#pragma unroll
  for (int c = 0; c < 3; ++c) v[c] = *(const f32x4*)(xr + c * 256 + lane * 4);
  float s = 0.f;
#pragma unroll
  for (int c = 0; c < 3; ++c)
#pragma unroll
    for (int j = 0; j < 4; ++j) s += v[c][j];
#pragma unroll
  for (int o = 32; o; o >>= 1) s += __shfl_xor(s, o);
  const float mu = s * (1.0f / D_MODEL);
  float vs = 0.f;
#pragma unroll
  for (int c = 0; c < 3; ++c)
#pragma unroll
    for (int j = 0; j < 4; ++j) { float d = v[c][j] - mu; vs += d * d; }
#pragma unroll
  for (int o = 32; o; o >>= 1) vs += __shfl_xor(vs, o);
  const float rs = rsqrtf(vs * (1.0f / D_MODEL) + 1e-5f);
  unsigned short* orow = out + row * D_MODEL;
#pragma unroll
  for (int c = 0; c < 3; ++c) {
    us4 o4;
#pragma unroll
    for (int j = 0; j < 4; ++j) {
      int idx = c * 256 + lane * 4 + j;
      o4[j] = f2bf((v[c][j] - mu) * rs * gam[idx] + bet[idx]);
    }
    *(us4*)(orow + c * 256 + lane * 4) = o4;
  }
}

// ------------- weight transpose + cast: W[K][Nc] f32 -> Wt[Nc][K] bf16 -------
__global__ __launch_bounds__(256)
void wtrans_kernel(const float* __restrict__ W, unsigned short* __restrict__ Wt,
                   int K, int Nc) {
  __shared__ float t[32][33];
  const int tx = threadIdx.x & 31, ty = threadIdx.x >> 5;  // 32x8
  const int nb = blockIdx.x * 32, kb = blockIdx.y * 32;
#pragma unroll
  for (int i = 0; i < 4; ++i)
    t[ty + 8 * i][tx] = W[(size_t)(kb + ty + 8 * i) * Nc + nb + tx];
  __syncthreads();
#pragma unroll
  for (int i = 0; i < 4; ++i)
    Wt[(size_t)(nb + ty + 8 * i) * K + kb + tx] = f2bf(t[tx][ty + 8 * i]);
}

// ------ bias reshape: rel[H][N][N] f32 -> biasF bf16 in S^T-fragment order,
// PRE-SCALED by log2(e) (softmax runs in log2 domain). Lane l: q = qt*32+(l&31);
// reg r: k = kt*32 + (r&3) + 8*(r>>2) + 4*(l>>5). Packed (r0,r1)(r2,r3)..
__global__ __launch_bounds__(256)
void brelayout_kernel(const float* __restrict__ rel, unsigned short* __restrict__ bF) {
  const int gw = blockIdx.x * 4 + (threadIdx.x >> 6);  // (h*32+qt)*32+ktg
  const int lane = threadIdx.x & 63;
  const int ktg = gw & 31, qt = (gw >> 5) & 31, h = gw >> 10;
  const int q = qt * 32 + (lane & 31), hi = lane >> 5;
  const float* src = rel + ((size_t)h * SEQ + q) * SEQ + ktg * 32 + 4 * hi;
  const float L2E = 1.4426950408889634f;
  unsigned ow[8];
#pragma unroll
  for (int g = 0; g < 4; ++g) {
    f32x4 v = *(const f32x4*)(src + g * 8);
    asm("v_cvt_pk_bf16_f32 %0, %1, %2" : "=v"(ow[2 * g])     : "v"(v[0] * L2E), "v"(v[1] * L2E));
    asm("v_cvt_pk_bf16_f32 %0, %1, %2" : "=v"(ow[2 * g + 1]) : "v"(v[2] * L2E), "v"(v[3] * L2E));
  }
  unsigned short* dst = bF + (((size_t)gw) * 64 + lane) * 16;
  *(uint4*)(dst)     = make_uint4(ow[0], ow[1], ow[2], ow[3]);
  *(uint4*)(dst + 8) = make_uint4(ow[4], ow[5], ow[6], ow[7]);
}

#define MODE_QKV  0
#define MODE_PROJ 1
#define MODE_FFN1 2
#define MODE_FFN2 3

// -------- GEMM (QKV only): 128x128, BK=64, 4 waves, 2-phase dbuf (R6) -------
template <int MODE>
__global__ __launch_bounds__(256)
void gemm_bt(const unsigned short* __restrict__ A, const unsigned short* __restrict__ Bt,
             int K, const float* __restrict__ bias, const float* __restrict__ resid,
             float* __restrict__ outF, unsigned short* __restrict__ o0,
             unsigned short* __restrict__ o1, unsigned short* __restrict__ o2) {
  __shared__ alignas(16) unsigned short smem[2][2][128 * 64];  // [A/B][buf][tile]
  const int tid = threadIdx.x;
  const int w = tid >> 6, lane = tid & 63;
  const int l31 = lane & 31, hi = lane >> 5;
  const int wm = w >> 1, wn = w & 1;
  const int nwg = gridDim.x * gridDim.y;
  const int bid0 = blockIdx.y * gridDim.x + blockIdx.x;
  const int cpx = nwg >> 3;
  const int bid = (bid0 & 7) * cpx + (bid0 >> 3);
  const int bx = bid % gridDim.x, by = bid / gridDim.x;
  const size_t m0 = (size_t)by * 128;
  const size_t n0 = (size_t)bx * 128;
  const unsigned short* gA = A + m0 * K;
  const unsigned short* gB = Bt + n0 * K;

  const int r8 = lane >> 3;
  const int u8 = lane & 7;
  const int ucol = (u8 ^ r8) * 8;

  f32x16 acc[2][2];
#pragma unroll
  for (int i = 0; i < 2; ++i)
#pragma unroll
    for (int j = 0; j < 2; ++j) acc[i][j] = (f32x16)(0.f);
  const int nk = K >> 6;

  auto stage = [&](int buf, int kt) {
#pragma unroll
    for (int g = 0; g < 4; ++g) {
      const int rowb = w * 32 + g * 8;
      gload_lds16(gA + (size_t)(rowb + r8) * K + kt * 64 + ucol, &smem[0][buf][rowb * 64]);
      gload_lds16(gB + (size_t)(rowb + r8) * K + kt * 64 + ucol, &smem[1][buf][rowb * 64]);
    }
  };

  const int swr = l31 & 7;
  const int rA = (wm * 64 + l31) * 64;
  const int rB = (wn * 64 + l31) * 64;

  stage(0, 0);
  __syncthreads();
  for (int kt = 0; kt < nk; ++kt) {
    const int buf = kt & 1;
    if (kt + 1 < nk) stage(buf ^ 1, kt + 1);
    bf16x8 af[2][4], bf[2][4];
#pragma unroll
    for (int mt = 0; mt < 2; ++mt)
#pragma unroll
      for (int ks = 0; ks < 4; ++ks) {
        af[mt][ks] = *(const bf16x8*)&smem[0][buf][rA + mt * 2048 + (((ks * 2 + hi) ^ swr) * 8)];
        bf[mt][ks] = *(const bf16x8*)&smem[1][buf][rB + mt * 2048 + (((ks * 2 + hi) ^ swr) * 8)];
      }
#pragma unroll
    for (int mt = 0; mt < 2; ++mt)
#pragma unroll
      for (int nt = 0; nt < 2; ++nt)
#pragma unroll
        for (int ks = 0; ks < 4; ++ks)
          acc[mt][nt] = mfma32(af[mt][ks], bf[nt][ks], acc[mt][nt]);
    __syncthreads();
  }

  // ---- V-region of QKV: transpose through (now dead) LDS, coalesced stores
  if constexpr (MODE == MODE_QKV) {
    if (bx >= 12) {
      unsigned short* tb = &smem[0][0][0];  // [128 n][136 m]
#pragma unroll
      for (int mt = 0; mt < 2; ++mt)
#pragma unroll
        for (int nt = 0; nt < 2; ++nt)
#pragma unroll
          for (int r = 0; r < 16; ++r) {
            const int nl = wn * 64 + nt * 32 + l31;
            const int ml = wm * 64 + mt * 32 + (r & 3) + 8 * (r >> 2) + 4 * hi;
            tb[nl * 136 + ml] = f2bf(acc[mt][nt][r] + bias[(int)n0 + nl]);
          }
      __syncthreads();
      const int rr = tid & 127, half = tid >> 7;
      const int n2 = ((int)n0 - 1536) + rr;
      const int hh = n2 >> 6, dh = n2 & 63;
      const int b2 = (int)(m0 >> 10), nq0 = (int)(m0 & 1023);
      unsigned short* dst = o2 + ((size_t)(b2 * NH + hh) * DHD + dh) * SEQ + nq0 + half * 64;
      const unsigned short* src = tb + rr * 136 + half * 64;
#pragma unroll
      for (int i = 0; i < 4; ++i)
        *(uint4*)(dst + i * 8) = *(const uint4*)(src + i * 8);
      return;
    }
  }

#pragma unroll
  for (int mt = 0; mt < 2; ++mt) {
#pragma unroll
    for (int nt = 0; nt < 2; ++nt) {
#pragma unroll
      for (int r = 0; r < 16; ++r) {
        const int m = (int)m0 + wm * 64 + mt * 32 + (r & 3) + 8 * (r >> 2) + 4 * hi;
        const int n = (int)n0 + wn * 64 + nt * 32 + l31;
        float v = acc[mt][nt][r] + bias[n];
        if constexpr (MODE == MODE_QKV) {
          const int b = m >> 10, nq = m & 1023;
          if (n < 768) {
            // Q: pre-scale by 0.125*log2(e) (softmax runs in log2 domain)
            const int h = n >> 6, dh = n & 63;
            o0[(((size_t)(b * NH + h)) * SEQ + nq) * DHD + dh] =
                f2bf(v * 0.1803368801111244f);
          } else {
            const int n2 = n - 768, h = n2 >> 6, dh = n2 & 63;
            o1[(((size_t)(b * NH + h)) * SEQ + nq) * DHD + dh] = f2bf(v);
          }
        } else if constexpr (MODE == MODE_PROJ) {
          const size_t off = (size_t)m * D_MODEL + n;
          outF[off] = v + resid[off];
        }
      }
    }
  }
}

// -------- GEMM 512-thread: 128x128, BK=64, 8 waves of 64x32 (PROJ/FFN) ------
// Same proven 2-phase dbuf + syncthreads; 2 blocks/CU x 8 waves = 16 waves/CU
// (2x the 256-thread version) to hide the barrier drain. Elementwise epilogues.
template <int MODE>
__global__ __launch_bounds__(512)
void gemm512(const unsigned short* __restrict__ A, const unsigned short* __restrict__ Bt,
             int K, const float* __restrict__ bias, const float* __restrict__ resid,
             float* __restrict__ outF, unsigned short* __restrict__ o0) {
  __shared__ alignas(16) unsigned short smem[2][2][128 * 64];  // 64KB
  const int tid = threadIdx.x;
  const int w = tid >> 6, lane = tid & 63;
  const int l31 = lane & 31, hi = lane >> 5;
  const int wm = w >> 2, wn = w & 3;   // wave tile: rows wm*64+[0,64), cols wn*32+[0,32)
  const int nwg = gridDim.x * gridDim.y;
  const int bid0 = blockIdx.y * gridDim.x + blockIdx.x;
  const int cpx = nwg >> 3;
  const int bid = (bid0 & 7) * cpx + (bid0 >> 3);
  const int bx = bid % gridDim.x, by = bid / gridDim.x;
  const size_t m0 = (size_t)by * 128;
  const size_t n0 = (size_t)bx * 128;
  const unsigned short* gA = A + m0 * K;
  const unsigned short* gB = Bt + n0 * K;

  const int r8 = lane >> 3;
  const int u8 = lane & 7;
  const int ucol = (u8 ^ r8) * 8;

  f32x16 acc[2];
  acc[0] = (f32x16)(0.f);
  acc[1] = (f32x16)(0.f);
  const int nk = K >> 6;

  // 8 waves x 16 rows each: 2 gloads per matrix per thread
  auto stage = [&](int buf, int kt) {
#pragma unroll
    for (int g = 0; g < 2; ++g) {
      const int rowb = w * 16 + g * 8;
      gload_lds16(gA + (size_t)(rowb + r8) * K + kt * 64 + ucol, &smem[0][buf][rowb * 64]);
      gload_lds16(gB + (size_t)(rowb + r8) * K + kt * 64 + ucol, &smem[1][buf][rowb * 64]);
    }
  };

  const int swr = l31 & 7;
  const int rA = (wm * 64 + l31) * 64;
  const int rB = (wn * 32 + l31) * 64;

  stage(0, 0);
  __syncthreads();
  for (int kt = 0; kt < nk; ++kt) {
    const int buf = kt & 1;
    if (kt + 1 < nk) stage(buf ^ 1, kt + 1);
    bf16x8 af[2][4], bf[4];
#pragma unroll
    for (int ks = 0; ks < 4; ++ks) {
      const int uo = ((ks * 2 + hi) ^ swr) * 8;
      af[0][ks] = *(const bf16x8*)&smem[0][buf][rA + uo];
      af[1][ks] = *(const bf16x8*)&smem[0][buf][rA + 2048 + uo];
      bf[ks]    = *(const bf16x8*)&smem[1][buf][rB + uo];
    }
    __builtin_amdgcn_s_setprio(1);
#pragma unroll
    for (int mt = 0; mt < 2; ++mt)
#pragma unroll
      for (int ks = 0; ks < 4; ++ks)
        acc[mt] = mfma32(af[mt][ks], bf[ks], acc[mt]);
    __builtin_amdgcn_s_setprio(0);
    __syncthreads();
  }

#pragma unroll
  for (int mt = 0; mt < 2; ++mt) {
#pragma unroll
    for (int r = 0; r < 16; ++r) {
      const int m = (int)m0 + wm * 64 + mt * 32 + (r & 3) + 8 * (r >> 2) + 4 * hi;
      const int n = (int)n0 + wn * 32 + l31;
      float v = acc[mt][r] + bias[n];
      if constexpr (MODE == MODE_FFN1) {
        // gelu(v) = v * sigmoid(1.5957691*(v+0.044715 v^3)); exp2 form:
        // u = v*(c1 + c2*v^2), e = 2^u, out = v * rcp(1+e)
        const float t = v * v;
        const float s = fmaf(-0.10295276f, t, -2.3022164f);  // c2 = c1*0.044715
        const float e = __builtin_amdgcn_exp2f(v * s);
        o0[(size_t)m * DFF + n] = f2bf(v * __builtin_amdgcn_rcpf(1.0f + e));
      } else {  // PROJ / FFN2: residual add, fp32 out
        const size_t off = (size_t)m * D_MODEL + n;
        outF[off] = v + resid[off];
      }
    }
  }
}

// ------- fused flash attention: 4 waves x 32 q-rows, 32x32x16 MFMA ----------
__global__ __launch_bounds__(256, 4)
void attn_kernel(const unsigned short* __restrict__ q, const unsigned short* __restrict__ k,
                 const unsigned short* __restrict__ vt, const unsigned short* __restrict__ bF,
                 unsigned short* __restrict__ ctx) {
  __shared__ alignas(16) unsigned short kv[2][16][64 * 8];
  const int tid = threadIdx.x, w = tid >> 6, lane = tid & 63;
  const int l31 = lane & 31, hi = lane >> 5;
  const int bid = (blockIdx.x & 7) * 96 + (blockIdx.x >> 3);
  const int bh = bid >> 3, qblk = bid & 7;
  const int b = bh / NH, h = bh % NH;
  const int q0w = qblk * 128 + w * 32;
  const unsigned short* qp = q + (size_t)bh * SEQ * DHD;
  const unsigned short* kp = k + (size_t)bh * SEQ * DHD;
  const unsigned short* vp = vt + (size_t)bh * DHD * SEQ;
  const unsigned short* bfp = bF + ((((size_t)(h * 32 + qblk * 4 + w)) * 32) * 64 + lane) * 16;

  bf16x8 Qf[4];
#pragma unroll
  for (int ds = 0; ds < 4; ++ds)
    Qf[ds] = *(const bf16x8*)(qp + (size_t)(q0w + l31) * DHD + ds * 16 + hi * 8);

  f32x16 o[2];
#pragma unroll
  for (int dt = 0; dt < 2; ++dt) o[dt] = (f32x16)(0.f);
  float mrun = -INFINITY, lrun = 0.f;

  auto stage = [&](int buf, int kb) {
    if (w < 2) {
      const unsigned short* g0 = kp + (size_t)(kb * 64 + w * 32 + l31) * DHD + hi * 8;
#pragma unroll
      for (int ds = 0; ds < 4; ++ds)
        gload_lds16(g0 + ds * 16, &kv[buf][w * 4 + ds][0]);
    } else {
      const int dt = w - 2;
      const unsigned short* g0 = vp + (size_t)(dt * 32 + l31) * SEQ + kb * 64 + hi * 8;
#pragma unroll
      for (int kh = 0; kh < 4; ++kh)
        gload_lds16(g0 + kh * 16, &kv[buf][8 + dt * 4 + kh][0]);
    }
  };

  stage(0, 0);
  __syncthreads();
  for (int kb = 0; kb < SEQ / 64; ++kb) {
    const int buf = kb & 1;
    if (kb + 1 < SEQ / 64) stage(buf ^ 1, kb + 1);

    f32x16 s0 = (f32x16)(0.f), s1 = (f32x16)(0.f);
    __builtin_amdgcn_s_setprio(1);
#pragma unroll
    for (int ds = 0; ds < 4; ++ds) {
      bf16x8 kf0 = *(const bf16x8*)&kv[buf][ds][lane * 8];
      s0 = mfma32(kf0, Qf[ds], s0);
      bf16x8 kf1 = *(const bf16x8*)&kv[buf][4 + ds][lane * 8];
      s1 = mfma32(kf1, Qf[ds], s1);
    }
    __builtin_amdgcn_s_setprio(0);

    const unsigned short* bb = bfp + (size_t)(kb * 2) * 64 * 16;
    uint4 a0 = *(const uint4*)(bb),            a1 = *(const uint4*)(bb + 8);
    uint4 c0 = *(const uint4*)(bb + 64 * 16),  c1 = *(const uint4*)(bb + 64 * 16 + 8);
    unsigned uw0[8] = {a0.x, a0.y, a0.z, a0.w, a1.x, a1.y, a1.z, a1.w};
    unsigned uw1[8] = {c0.x, c0.y, c0.z, c0.w, c1.x, c1.y, c1.z, c1.w};
    float p0[16], p1[16];
#pragma unroll
    for (int j = 0; j < 8; ++j) {
      p0[2 * j]     = s0[2 * j]     + __uint_as_float(uw0[j] << 16);
      p0[2 * j + 1] = s0[2 * j + 1] + __uint_as_float(uw0[j] & 0xffff0000u);
      p1[2 * j]     = s1[2 * j]     + __uint_as_float(uw1[j] << 16);
      p1[2 * j + 1] = s1[2 * j + 1] + __uint_as_float(uw1[j] & 0xffff0000u);
    }

    float pmax = p0[0];
#pragma unroll
    for (int i = 1; i < 16; ++i) pmax = fmaxf(pmax, p0[i]);
#pragma unroll
    for (int i = 0; i < 16; ++i) pmax = fmaxf(pmax, p1[i]);
    if (!__all(pmax - mrun <= 11.0f)) {
      float pm = fmaxf(pmax, __shfl_xor(pmax, 32));
      const float mn = fmaxf(mrun, pm);
      const float al = __builtin_amdgcn_exp2f(mrun - mn);
      mrun = mn;
      lrun *= al;
#pragma unroll
      for (int dt = 0; dt < 2; ++dt)
#pragma unroll
        for (int r = 0; r < 16; ++r) o[dt][r] *= al;
    }
#pragma unroll
    for (int i = 0; i < 16; ++i) { p0[i] = __builtin_amdgcn_exp2f(p0[i] - mrun); lrun += p0[i]; }
#pragma unroll
    for (int i = 0; i < 16; ++i) { p1[i] = __builtin_amdgcn_exp2f(p1[i] - mrun); lrun += p1[i]; }

    unsigned wpk[16];
#pragma unroll
    for (int i = 0; i < 8; ++i) {
      asm("v_cvt_pk_bf16_f32 %0, %1, %2" : "=v"(wpk[i])     : "v"(p0[2 * i]), "v"(p0[2 * i + 1]));
      asm("v_cvt_pk_bf16_f32 %0, %1, %2" : "=v"(wpk[8 + i]) : "v"(p1[2 * i]), "v"(p1[2 * i + 1]));
    }
    plswap(wpk[0], wpk[2]);   plswap(wpk[1], wpk[3]);
    plswap(wpk[4], wpk[6]);   plswap(wpk[5], wpk[7]);
    plswap(wpk[8], wpk[10]);  plswap(wpk[9], wpk[11]);
    plswap(wpk[12], wpk[14]); plswap(wpk[13], wpk[15]);
    bf16x8 pf[4];
    pf[0] = mk8(wpk[0], wpk[1], wpk[2], wpk[3]);
    pf[1] = mk8(wpk[4], wpk[5], wpk[6], wpk[7]);
    pf[2] = mk8(wpk[8], wpk[9], wpk[10], wpk[11]);
    pf[3] = mk8(wpk[12], wpk[13], wpk[14], wpk[15]);

    __builtin_amdgcn_s_setprio(1);
#pragma unroll
    for (int dt = 0; dt < 2; ++dt)
#pragma unroll
      for (int kh = 0; kh < 4; ++kh) {
        bf16x8 vf = *(const bf16x8*)&kv[buf][8 + dt * 4 + kh][lane * 8];
        o[dt] = mfma32(vf, pf[kh], o[dt]);
      }
    __builtin_amdgcn_s_setprio(0);

    __syncthreads();
  }

  lrun += __shfl_xor(lrun, 32);
  const float inv = 1.0f / lrun;
  unsigned short* crow = ctx + ((size_t)b * SEQ + q0w + l31) * D_MODEL + h * DHD;
#pragma unroll
  for (int dt = 0; dt < 2; ++dt)
#pragma unroll
    for (int g = 0; g < 4; ++g) {
      us4 ov;
#pragma unroll
      for (int j = 0; j < 4; ++j) ov[j] = f2bf(o[dt][4 * g + j] * inv);
      *(us4*)(crow + dt * 32 + g * 8 + 4 * hi) = ov;
    }
}

// ----------------------------------------------------------------------------
extern "C" void kernel_launch(void* const* d_in, const int* in_sizes, int n_in,
                              void* d_out, int out_size, void* d_ws, size_t ws_size,
                              hipStream_t stream) {
  (void)in_sizes; (void)n_in; (void)out_size; (void)ws_size;
  const float* x     = (const float*)d_in[0];
  const float* ln1_g = (const float*)d_in[1];
  const float* ln1_b = (const float*)d_in[2];
  const float* wqkv  = (const float*)d_in[3];
  const float* bqkv  = (const float*)d_in[4];
  const float* wo    = (const float*)d_in[5];
  const float* bo    = (const float*)d_in[6];
  const float* rel   = (const float*)d_in[7];
  const float* ln2_g = (const float*)d_in[8];
  const float* ln2_b = (const float*)d_in[9];
  const float* w1    = (const float*)d_in[10];
  const float* b1    = (const float*)d_in[11];
  const float* w2    = (const float*)d_in[12];
  const float* b2    = (const float*)d_in[13];
  float* out = (float*)d_out;

  char* p = (char*)d_ws;
  auto take = [&](size_t bytes) {
    void* r = (void*)p;
    p += (bytes + 255) & ~(size_t)255;
    return r;
  };
  unsigned short* hbuf  = (unsigned short*)take((size_t)NTOK * D_MODEL * 2);
  unsigned short* wqkvT = (unsigned short*)take((size_t)2304 * 768 * 2);
  unsigned short* woT   = (unsigned short*)take((size_t)768 * 768 * 2);
  unsigned short* w1T   = (unsigned short*)take((size_t)3072 * 768 * 2);
  unsigned short* w2T   = (unsigned short*)take((size_t)768 * 3072 * 2);
  unsigned short* qbuf  = (unsigned short*)take((size_t)8 * NH * SEQ * DHD * 2);
  unsigned short* kbuf  = (unsigned short*)take((size_t)8 * NH * SEQ * DHD * 2);
  unsigned short* vtbuf = (unsigned short*)take((size_t)8 * NH * SEQ * DHD * 2);
  unsigned short* ctxb  = (unsigned short*)take((size_t)NTOK * D_MODEL * 2);
  unsigned short* h1buf = (unsigned short*)take((size_t)NTOK * DFF * 2);
  // biasF (25.2 MB) aliases h1buf (50.3 MB): dead before FFN1 writes h1buf.
  unsigned short* biasF = h1buf;
  // x2 (post-attention residual stream) lives in d_out (fp32).

  // weight prep (independent of activations)
  wtrans_kernel<<<dim3(2304 / 32, 768 / 32), 256, 0, stream>>>(wqkv, wqkvT, 768, 2304);
  wtrans_kernel<<<dim3(768 / 32, 768 / 32), 256, 0, stream>>>(wo, woT, 768, 768);
  wtrans_kernel<<<dim3(3072 / 32, 768 / 32), 256, 0, stream>>>(w1, w1T, 768, 3072);
  wtrans_kernel<<<dim3(768 / 32, 3072 / 32), 256, 0, stream>>>(w2, w2T, 3072, 768);
  // bias -> bf16 fragment order (pre-scaled by log2 e)
  brelayout_kernel<<<NH * 32 * 32 / 4, 256, 0, stream>>>(rel, biasF);

  // LN1: x -> h (bf16)
  ln_kernel<<<NTOK / 4, 256, 0, stream>>>(x, ln1_g, ln1_b, hbuf);
  // QKV: h @ wqkv + bqkv -> q (pre-scaled), k, Vt (bf16, attention layouts)
  gemm_bt<MODE_QKV><<<dim3(2304 / 128, NTOK / 128), 256, 0, stream>>>(
      hbuf, wqkvT, 768, bqkv, nullptr, nullptr, qbuf, kbuf, vtbuf);
  // attention -> ctx (bf16, [tok][D])
  attn_kernel<<<8 * NH * (SEQ / 128), 256, 0, stream>>>(qbuf, kbuf, vtbuf, biasF, ctxb);
  // proj: ctx @ wo + bo + x -> x2 (fp32, in d_out)
  gemm512<MODE_PROJ><<<dim3(768 / 128, NTOK / 128), 512, 0, stream>>>(
      ctxb, woT, 768, bo, x, out, nullptr);
  // LN2: x2 -> h2 (bf16, reuse hbuf)
  ln_kernel<<<NTOK / 4, 256, 0, stream>>>(out, ln2_g, ln2_b, hbuf);
  // FFN1: h2 @ w1 + b1, gelu -> h1 (bf16)
  gemm512<MODE_FFN1><<<dim3(DFF / 128, NTOK / 128), 512, 0, stream>>>(
      hbuf, w1T, 768, b1, nullptr, nullptr, h1buf);
  // FFN2: h1 @ w2 + b2 + x2 -> out (fp32, in place on d_out)
  gemm512<MODE_FFN2><<<dim3(768 / 128, NTOK / 128), 512, 0, stream>>>(
      h1buf, w2T, 3072, b2, out, out, nullptr);
}

// Round 10
// 255.936 us; speedup vs baseline: 1.1680x; 1.1000x over previous
//
#include <hip/hip_runtime.h>
#include <hip/hip_bf16.h>
#include <math.h>

#define D_MODEL 768
#define NTOK    8192   // B*N
#define SEQ     1024
#define NH      12
#define DHD     64
#define DFF     3072

typedef __attribute__((ext_vector_type(8)))  __bf16 bf16x8;
typedef __attribute__((ext_vector_type(4)))  float  f32x4;
typedef __attribute__((ext_vector_type(16))) float  f32x16;
typedef __attribute__((ext_vector_type(4)))  unsigned short us4;

typedef const __attribute__((address_space(1))) void g_void;
typedef __attribute__((address_space(3))) void lds_void;

__device__ __forceinline__ unsigned short f2bf(float f) {
  unsigned u = __float_as_uint(f);
  u += 0x7fffu + ((u >> 16) & 1u);   // RNE to bf16
  return (unsigned short)(u >> 16);
}

__device__ __forceinline__ f32x16 mfma32(bf16x8 a, bf16x8 b, f32x16 c) {
  return __builtin_amdgcn_mfma_f32_32x32x16_bf16(a, b, c, 0, 0, 0);
}

// async global->LDS, 16B per lane; LDS dest = uniform base + lane*16
__device__ __forceinline__ void gload_lds16(const unsigned short* g, unsigned short* l) {
  __builtin_amdgcn_global_load_lds((g_void*)g, (lds_void*)l, 16, 0, 0);
}

// v_permlane32_swap_b32: a[32..63] <-> b[0..31] (both operands updated)
__device__ __forceinline__ void plswap(unsigned &a, unsigned &b) {
  asm("v_permlane32_swap_b32 %0, %1" : "+v"(a), "+v"(b));
}
__device__ __forceinline__ bf16x8 mk8(unsigned a, unsigned b, unsigned c, unsigned d) {
  union { unsigned u[4]; bf16x8 v; } t;
  t.u[0] = a; t.u[1] = b; t.u[2] = c; t.u[3] = d;
  return t.v;
}

// ---------------- LayerNorm row body: one wave per row of 768 ----------------
__device__ __forceinline__ void ln_row(const float* __restrict__ x,
                                       const float* __restrict__ gam,
                                       const float* __restrict__ bet,
                                       unsigned short* __restrict__ out,
                                       size_t row, int lane) {
  const float* xr = x + row * D_MODEL;
  f32x4 v[3];
#pragma unroll
  for (int c = 0; c < 3; ++c) v[c] = *(const f32x4*)(xr + c * 256 + lane * 4);
  float s = 0.f;
#pragma unroll
  for (int c = 0; c < 3; ++c)
#pragma unroll
    for (int j = 0; j < 4; ++j) s += v[c][j];
#pragma unroll
  for (int o = 32; o; o >>= 1) s += __shfl_xor(s, o);
  const float mu = s * (1.0f / D_MODEL);
  float vs = 0.f;
#pragma unroll
  for (int c = 0; c < 3; ++c)
#pragma unroll
    for (int j = 0; j < 4; ++j) { float d = v[c][j] - mu; vs += d * d; }
#pragma unroll
  for (int o = 32; o; o >>= 1) vs += __shfl_xor(vs, o);
  const float rs = rsqrtf(vs * (1.0f / D_MODEL) + 1e-5f);
  unsigned short* orow = out + row * D_MODEL;
#pragma unroll
  for (int c = 0; c < 3; ++c) {
    us4 o4;
#pragma unroll
    for (int j = 0; j < 4; ++j) {
      int idx = c * 256 + lane * 4 + j;
      o4[j] = f2bf((v[c][j] - mu) * rs * gam[idx] + bet[idx]);
    }
    *(us4*)(orow + c * 256 + lane * 4) = o4;
  }
}

// LN2 standalone (depends on proj output)
__global__ __launch_bounds__(256)
void ln_kernel(const float* __restrict__ x, const float* __restrict__ gam,
               const float* __restrict__ bet, unsigned short* __restrict__ out) {
  ln_row(x, gam, bet, out, (size_t)blockIdx.x * 4 + (threadIdx.x >> 6), threadIdx.x & 63);
}

// ------------- weight transpose body: W[K][Nc] f32 -> Wt[Nc][K] bf16 ---------
__device__ __forceinline__ void wtrans_body(const float* __restrict__ W,
                                            unsigned short* __restrict__ Wt,
                                            int K, int Nc, int bx, int by, int tid) {
  __shared__ float t[32][33];
  const int tx = tid & 31, ty = tid >> 5;  // 32x8
  const int nb = bx * 32, kb = by * 32;
#pragma unroll
  for (int i = 0; i < 4; ++i)
    t[ty + 8 * i][tx] = W[(size_t)(kb + ty + 8 * i) * Nc + nb + tx];
  __syncthreads();
#pragma unroll
  for (int i = 0; i < 4; ++i)
    Wt[(size_t)(nb + ty + 8 * i) * K + kb + tx] = f2bf(t[tx][ty + 8 * i]);
}

// ------ bias reshape body: rel[H][N][N] f32 -> biasF bf16, S^T-fragment order,
// pre-scaled by log2(e). Lane l: q = qt*32+(l&31); reg r: k = kt*32 + (r&3) +
// 8*(r>>2) + 4*(l>>5). Packed (r0,r1)(r2,r3)..
__device__ __forceinline__ void brelayout_body(const float* __restrict__ rel,
                                               unsigned short* __restrict__ bF,
                                               int blk, int tid) {
  const int gw = blk * 4 + (tid >> 6);  // (h*32+qt)*32+ktg
  const int lane = tid & 63;
  const int ktg = gw & 31, qt = (gw >> 5) & 31, h = gw >> 10;
  const int q = qt * 32 + (lane & 31), hi = lane >> 5;
  const float* src = rel + ((size_t)h * SEQ + q) * SEQ + ktg * 32 + 4 * hi;
  const float L2E = 1.4426950408889634f;
  unsigned ow[8];
#pragma unroll
  for (int g = 0; g < 4; ++g) {
    f32x4 v = *(const f32x4*)(src + g * 8);
    asm("v_cvt_pk_bf16_f32 %0, %1, %2" : "=v"(ow[2 * g])     : "v"(v[0] * L2E), "v"(v[1] * L2E));
    asm("v_cvt_pk_bf16_f32 %0, %1, %2" : "=v"(ow[2 * g + 1]) : "v"(v[2] * L2E), "v"(v[3] * L2E));
  }
  unsigned short* dst = bF + (((size_t)gw) * 64 + lane) * 16;
  *(uint4*)(dst)     = make_uint4(ow[0], ow[1], ow[2], ow[3]);
  *(uint4*)(dst + 8) = make_uint4(ow[4], ow[5], ow[6], ow[7]);
}

// ---- fused preprocessing: 4x weight transpose + bias relayout + LN1 --------
// All independent of each other (inputs: weights, rel, x). One launch.
#define WP0 1728            // wqkv:   (2304/32=72) x (768/32=24)
#define WP1 (WP0 + 576)     // wo:     24 x 24
#define WP2 (WP1 + 2304)    // w1:     96 x 24
#define WP3 (WP2 + 2304)    // w2:     24 x 96
#define WP4 (WP3 + 3072)    // brelayout: 12288/4
#define WP5 (WP4 + 2048)    // ln1: 8192/4
__global__ __launch_bounds__(256)
void wprep_kernel(const float* __restrict__ wqkv, unsigned short* __restrict__ wqkvT,
                  const float* __restrict__ wo, unsigned short* __restrict__ woT,
                  const float* __restrict__ w1, unsigned short* __restrict__ w1T,
                  const float* __restrict__ w2, unsigned short* __restrict__ w2T,
                  const float* __restrict__ rel, unsigned short* __restrict__ biasF,
                  const float* __restrict__ x, const float* __restrict__ ln1_g,
                  const float* __restrict__ ln1_b, unsigned short* __restrict__ hbuf) {
  const int b = blockIdx.x, tid = threadIdx.x;
  if (b < WP0)      wtrans_body(wqkv, wqkvT, 768, 2304, b % 72, b / 72, tid);
  else if (b < WP1) wtrans_body(wo, woT, 768, 768, (b - WP0) % 24, (b - WP0) / 24, tid);
  else if (b < WP2) wtrans_body(w1, w1T, 768, 3072, (b - WP1) % 96, (b - WP1) / 96, tid);
  else if (b < WP3) wtrans_body(w2, w2T, 3072, 768, (b - WP2) % 24, (b - WP2) / 24, tid);
  else if (b < WP4) brelayout_body(rel, biasF, b - WP3, tid);
  else              ln_row(x, ln1_g, ln1_b, hbuf,
                           (size_t)(b - WP4) * 4 + (tid >> 6), tid & 63);
}

// -------- GEMM: C[M][N] = A[M][K] @ Bt[N][K]^T, bf16, fused epilogue --------
// R6-proven: 128x128 tile, BK=64, 4 waves (wave tile 64x64 = 2x2 of 32x32x16),
// 2-phase LDS dbuf + __syncthreads. XOR-swizzle on per-lane GLOBAL source
// (gload dest linear) + ds_read col.
#define MODE_QKV  0
#define MODE_PROJ 1
#define MODE_FFN1 2
#define MODE_FFN2 3

template <int MODE>
__global__ __launch_bounds__(256)
void gemm_bt(const unsigned short* __restrict__ A, const unsigned short* __restrict__ Bt,
             int K, const float* __restrict__ bias, const float* __restrict__ resid,
             float* __restrict__ outF, unsigned short* __restrict__ o0,
             unsigned short* __restrict__ o1, unsigned short* __restrict__ o2) {
  __shared__ alignas(16) unsigned short smem[2][2][128 * 64];  // [A/B][buf][tile]
  const int tid = threadIdx.x;
  const int w = tid >> 6, lane = tid & 63;
  const int l31 = lane & 31, hi = lane >> 5;
  const int wm = w >> 1, wn = w & 1;
  const int nwg = gridDim.x * gridDim.y;
  const int bid0 = blockIdx.y * gridDim.x + blockIdx.x;
  const int cpx = nwg >> 3;
  const int bid = (bid0 & 7) * cpx + (bid0 >> 3);
  const int bx = bid % gridDim.x, by = bid / gridDim.x;
  const size_t m0 = (size_t)by * 128;
  const size_t n0 = (size_t)bx * 128;
  const unsigned short* gA = A + m0 * K;
  const unsigned short* gB = Bt + n0 * K;

  const int r8 = lane >> 3;
  const int u8 = lane & 7;
  const int ucol = (u8 ^ r8) * 8;

  f32x16 acc[2][2];
#pragma unroll
  for (int i = 0; i < 2; ++i)
#pragma unroll
    for (int j = 0; j < 2; ++j) acc[i][j] = (f32x16)(0.f);
  const int nk = K >> 6;

  auto stage = [&](int buf, int kt) {
#pragma unroll
    for (int g = 0; g < 4; ++g) {
      const int rowb = w * 32 + g * 8;
      gload_lds16(gA + (size_t)(rowb + r8) * K + kt * 64 + ucol, &smem[0][buf][rowb * 64]);
      gload_lds16(gB + (size_t)(rowb + r8) * K + kt * 64 + ucol, &smem[1][buf][rowb * 64]);
    }
  };

  const int swr = l31 & 7;
  const int rA = (wm * 64 + l31) * 64;
  const int rB = (wn * 64 + l31) * 64;

  stage(0, 0);
  __syncthreads();
  for (int kt = 0; kt < nk; ++kt) {
    const int buf = kt & 1;
    if (kt + 1 < nk) stage(buf ^ 1, kt + 1);
    bf16x8 af[2][4], bf[2][4];
#pragma unroll
    for (int mt = 0; mt < 2; ++mt)
#pragma unroll
      for (int ks = 0; ks < 4; ++ks) {
        af[mt][ks] = *(const bf16x8*)&smem[0][buf][rA + mt * 2048 + (((ks * 2 + hi) ^ swr) * 8)];
        bf[mt][ks] = *(const bf16x8*)&smem[1][buf][rB + mt * 2048 + (((ks * 2 + hi) ^ swr) * 8)];
      }
#pragma unroll
    for (int mt = 0; mt < 2; ++mt)
#pragma unroll
      for (int nt = 0; nt < 2; ++nt)
#pragma unroll
        for (int ks = 0; ks < 4; ++ks)
          acc[mt][nt] = mfma32(af[mt][ks], bf[nt][ks], acc[mt][nt]);
    __syncthreads();
  }

  // ---- V-region of QKV: transpose through (now dead) LDS, coalesced stores
  if constexpr (MODE == MODE_QKV) {
    if (bx >= 12) {
      unsigned short* tb = &smem[0][0][0];  // [128 n][136 m]
#pragma unroll
      for (int mt = 0; mt < 2; ++mt)
#pragma unroll
        for (int nt = 0; nt < 2; ++nt)
#pragma unroll
          for (int r = 0; r < 16; ++r) {
            const int nl = wn * 64 + nt * 32 + l31;
            const int ml = wm * 64 + mt * 32 + (r & 3) + 8 * (r >> 2) + 4 * hi;
            tb[nl * 136 + ml] = f2bf(acc[mt][nt][r] + bias[(int)n0 + nl]);
          }
      __syncthreads();
      const int rr = tid & 127, half = tid >> 7;
      const int n2 = ((int)n0 - 1536) + rr;
      const int hh = n2 >> 6, dh = n2 & 63;
      const int b2 = (int)(m0 >> 10), nq0 = (int)(m0 & 1023);
      unsigned short* dst = o2 + ((size_t)(b2 * NH + hh) * DHD + dh) * SEQ + nq0 + half * 64;
      const unsigned short* src = tb + rr * 136 + half * 64;
#pragma unroll
      for (int i = 0; i < 4; ++i)
        *(uint4*)(dst + i * 8) = *(const uint4*)(src + i * 8);
      return;
    }
  }

#pragma unroll
  for (int mt = 0; mt < 2; ++mt) {
#pragma unroll
    for (int nt = 0; nt < 2; ++nt) {
#pragma unroll
      for (int r = 0; r < 16; ++r) {
        const int m = (int)m0 + wm * 64 + mt * 32 + (r & 3) + 8 * (r >> 2) + 4 * hi;
        const int n = (int)n0 + wn * 64 + nt * 32 + l31;
        float v = acc[mt][nt][r] + bias[n];
        if constexpr (MODE == MODE_QKV) {
          const int b = m >> 10, nq = m & 1023;
          if (n < 768) {
            // Q: pre-scale by 0.125*log2(e) (softmax runs in log2 domain)
            const int h = n >> 6, dh = n & 63;
            o0[(((size_t)(b * NH + h)) * SEQ + nq) * DHD + dh] =
                f2bf(v * 0.1803368801111244f);
          } else {
            const int n2 = n - 768, h = n2 >> 6, dh = n2 & 63;
            o1[(((size_t)(b * NH + h)) * SEQ + nq) * DHD + dh] = f2bf(v);
          }
        } else if constexpr (MODE == MODE_PROJ) {
          const size_t off = (size_t)m * D_MODEL + n;
          outF[off] = v + resid[off];
        } else if constexpr (MODE == MODE_FFN1) {
          // gelu(v) = v * sigmoid(1.5957691*(v+0.044715 v^3)), exp2 form
          const float t = v * v;
          const float s = fmaf(-0.10295276f, t, -2.3022164f);
          const float e = __builtin_amdgcn_exp2f(v * s);
          o0[(size_t)m * DFF + n] = f2bf(v * __builtin_amdgcn_rcpf(1.0f + e));
        } else {  // FFN2: in-place residual on outF (x2 lives there)
          const size_t off = (size_t)m * D_MODEL + n;
          outF[off] = v + resid[off];
        }
      }
    }
  }
}

// ------- fused flash attention: 4 waves x 32 q-rows, 32x32x16 MFMA ----------
// K/V staged into LDS in fragment order (shared by all 4 waves); swapped
// operands: S^T[k][q] = mfma(K,Q) so q = lane&31, k = reg-mapped. Softmax in
// log2 domain (Q pre-scaled, biasF pre-scaled, exp2), fully in-lane with
// defer-max. P -> PV B-frags entirely in-register via cvt_pk + permlane32_swap.
__global__ __launch_bounds__(256, 4)
void attn_kernel(const unsigned short* __restrict__ q, const unsigned short* __restrict__ k,
                 const unsigned short* __restrict__ vt, const unsigned short* __restrict__ bF,
                 unsigned short* __restrict__ ctx) {
  __shared__ alignas(16) unsigned short kv[2][16][64 * 8];
  const int tid = threadIdx.x, w = tid >> 6, lane = tid & 63;
  const int l31 = lane & 31, hi = lane >> 5;
  const int bid = (blockIdx.x & 7) * 96 + (blockIdx.x >> 3);
  const int bh = bid >> 3, qblk = bid & 7;
  const int b = bh / NH, h = bh % NH;
  const int q0w = qblk * 128 + w * 32;
  const unsigned short* qp = q + (size_t)bh * SEQ * DHD;
  const unsigned short* kp = k + (size_t)bh * SEQ * DHD;
  const unsigned short* vp = vt + (size_t)bh * DHD * SEQ;
  const unsigned short* bfp = bF + ((((size_t)(h * 32 + qblk * 4 + w)) * 32) * 64 + lane) * 16;

  bf16x8 Qf[4];
#pragma unroll
  for (int ds = 0; ds < 4; ++ds)
    Qf[ds] = *(const bf16x8*)(qp + (size_t)(q0w + l31) * DHD + ds * 16 + hi * 8);

  f32x16 o[2];
#pragma unroll
  for (int dt = 0; dt < 2; ++dt) o[dt] = (f32x16)(0.f);
  float mrun = -INFINITY, lrun = 0.f;

  auto stage = [&](int buf, int kb) {
    if (w < 2) {
      const unsigned short* g0 = kp + (size_t)(kb * 64 + w * 32 + l31) * DHD + hi * 8;
#pragma unroll
      for (int ds = 0; ds < 4; ++ds)
        gload_lds16(g0 + ds * 16, &kv[buf][w * 4 + ds][0]);
    } else {
      const int dt = w - 2;
      const unsigned short* g0 = vp + (size_t)(dt * 32 + l31) * SEQ + kb * 64 + hi * 8;
#pragma unroll
      for (int kh = 0; kh < 4; ++kh)
        gload_lds16(g0 + kh * 16, &kv[buf][8 + dt * 4 + kh][0]);
    }
  };

  stage(0, 0);
  __syncthreads();
  for (int kb = 0; kb < SEQ / 64; ++kb) {
    const int buf = kb & 1;
    if (kb + 1 < SEQ / 64) stage(buf ^ 1, kb + 1);

    f32x16 s0 = (f32x16)(0.f), s1 = (f32x16)(0.f);
    __builtin_amdgcn_s_setprio(1);
#pragma unroll
    for (int ds = 0; ds < 4; ++ds) {
      bf16x8 kf0 = *(const bf16x8*)&kv[buf][ds][lane * 8];
      s0 = mfma32(kf0, Qf[ds], s0);
      bf16x8 kf1 = *(const bf16x8*)&kv[buf][4 + ds][lane * 8];
      s1 = mfma32(kf1, Qf[ds], s1);
    }
    __builtin_amdgcn_s_setprio(0);

    const unsigned short* bb = bfp + (size_t)(kb * 2) * 64 * 16;
    uint4 a0 = *(const uint4*)(bb),            a1 = *(const uint4*)(bb + 8);
    uint4 c0 = *(const uint4*)(bb + 64 * 16),  c1 = *(const uint4*)(bb + 64 * 16 + 8);
    unsigned uw0[8] = {a0.x, a0.y, a0.z, a0.w, a1.x, a1.y, a1.z, a1.w};
    unsigned uw1[8] = {c0.x, c0.y, c0.z, c0.w, c1.x, c1.y, c1.z, c1.w};
    float p0[16], p1[16];
#pragma unroll
    for (int j = 0; j < 8; ++j) {
      p0[2 * j]     = s0[2 * j]     + __uint_as_float(uw0[j] << 16);
      p0[2 * j + 1] = s0[2 * j + 1] + __uint_as_float(uw0[j] & 0xffff0000u);
      p1[2 * j]     = s1[2 * j]     + __uint_as_float(uw1[j] << 16);
      p1[2 * j + 1] = s1[2 * j + 1] + __uint_as_float(uw1[j] & 0xffff0000u);
    }

    float pmax = p0[0];
#pragma unroll
    for (int i = 1; i < 16; ++i) pmax = fmaxf(pmax, p0[i]);
#pragma unroll
    for (int i = 0; i < 16; ++i) pmax = fmaxf(pmax, p1[i]);
    if (!__all(pmax - mrun <= 11.0f)) {
      float pm = fmaxf(pmax, __shfl_xor(pmax, 32));
      const float mn = fmaxf(mrun, pm);
      const float al = __builtin_amdgcn_exp2f(mrun - mn);
      mrun = mn;
      lrun *= al;
#pragma unroll
      for (int dt = 0; dt < 2; ++dt)
#pragma unroll
        for (int r = 0; r < 16; ++r) o[dt][r] *= al;
    }
#pragma unroll
    for (int i = 0; i < 16; ++i) { p0[i] = __builtin_amdgcn_exp2f(p0[i] - mrun); lrun += p0[i]; }
#pragma unroll
    for (int i = 0; i < 16; ++i) { p1[i] = __builtin_amdgcn_exp2f(p1[i] - mrun); lrun += p1[i]; }

    unsigned wpk[16];
#pragma unroll
    for (int i = 0; i < 8; ++i) {
      asm("v_cvt_pk_bf16_f32 %0, %1, %2" : "=v"(wpk[i])     : "v"(p0[2 * i]), "v"(p0[2 * i + 1]));
      asm("v_cvt_pk_bf16_f32 %0, %1, %2" : "=v"(wpk[8 + i]) : "v"(p1[2 * i]), "v"(p1[2 * i + 1]));
    }
    plswap(wpk[0], wpk[2]);   plswap(wpk[1], wpk[3]);
    plswap(wpk[4], wpk[6]);   plswap(wpk[5], wpk[7]);
    plswap(wpk[8], wpk[10]);  plswap(wpk[9], wpk[11]);
    plswap(wpk[12], wpk[14]); plswap(wpk[13], wpk[15]);
    bf16x8 pf[4];
    pf[0] = mk8(wpk[0], wpk[1], wpk[2], wpk[3]);
    pf[1] = mk8(wpk[4], wpk[5], wpk[6], wpk[7]);
    pf[2] = mk8(wpk[8], wpk[9], wpk[10], wpk[11]);
    pf[3] = mk8(wpk[12], wpk[13], wpk[14], wpk[15]);

    __builtin_amdgcn_s_setprio(1);
#pragma unroll
    for (int dt = 0; dt < 2; ++dt)
#pragma unroll
      for (int kh = 0; kh < 4; ++kh) {
        bf16x8 vf = *(const bf16x8*)&kv[buf][8 + dt * 4 + kh][lane * 8];
        o[dt] = mfma32(vf, pf[kh], o[dt]);
      }
    __builtin_amdgcn_s_setprio(0);

    __syncthreads();
  }

  lrun += __shfl_xor(lrun, 32);
  const float inv = 1.0f / lrun;
  unsigned short* crow = ctx + ((size_t)b * SEQ + q0w + l31) * D_MODEL + h * DHD;
#pragma unroll
  for (int dt = 0; dt < 2; ++dt)
#pragma unroll
    for (int g = 0; g < 4; ++g) {
      us4 ov;
#pragma unroll
      for (int j = 0; j < 4; ++j) ov[j] = f2bf(o[dt][4 * g + j] * inv);
      *(us4*)(crow + dt * 32 + g * 8 + 4 * hi) = ov;
    }
}

// ----------------------------------------------------------------------------
extern "C" void kernel_launch(void* const* d_in, const int* in_sizes, int n_in,
                              void* d_out, int out_size, void* d_ws, size_t ws_size,
                              hipStream_t stream) {
  (void)in_sizes; (void)n_in; (void)out_size; (void)ws_size;
  const float* x     = (const float*)d_in[0];
  const float* ln1_g = (const float*)d_in[1];
  const float* ln1_b = (const float*)d_in[2];
  const float* wqkv  = (const float*)d_in[3];
  const float* bqkv  = (const float*)d_in[4];
  const float* wo    = (const float*)d_in[5];
  const float* bo    = (const float*)d_in[6];
  const float* rel   = (const float*)d_in[7];
  const float* ln2_g = (const float*)d_in[8];
  const float* ln2_b = (const float*)d_in[9];
  const float* w1    = (const float*)d_in[10];
  const float* b1    = (const float*)d_in[11];
  const float* w2    = (const float*)d_in[12];
  const float* b2    = (const float*)d_in[13];
  float* out = (float*)d_out;

  char* p = (char*)d_ws;
  auto take = [&](size_t bytes) {
    void* r = (void*)p;
    p += (bytes + 255) & ~(size_t)255;
    return r;
  };
  unsigned short* hbuf  = (unsigned short*)take((size_t)NTOK * D_MODEL * 2);
  unsigned short* wqkvT = (unsigned short*)take((size_t)2304 * 768 * 2);
  unsigned short* woT   = (unsigned short*)take((size_t)768 * 768 * 2);
  unsigned short* w1T   = (unsigned short*)take((size_t)3072 * 768 * 2);
  unsigned short* w2T   = (unsigned short*)take((size_t)768 * 3072 * 2);
  unsigned short* qbuf  = (unsigned short*)take((size_t)8 * NH * SEQ * DHD * 2);
  unsigned short* kbuf  = (unsigned short*)take((size_t)8 * NH * SEQ * DHD * 2);
  unsigned short* vtbuf = (unsigned short*)take((size_t)8 * NH * SEQ * DHD * 2);
  unsigned short* ctxb  = (unsigned short*)take((size_t)NTOK * D_MODEL * 2);
  unsigned short* h1buf = (unsigned short*)take((size_t)NTOK * DFF * 2);
  // biasF (25.2 MB) aliases h1buf (50.3 MB): dead before FFN1 writes h1buf.
  unsigned short* biasF = h1buf;
  // x2 (post-attention residual stream) lives in d_out (fp32).

  // fused preprocessing: 4x wtrans + bias relayout + LN1 (one launch)
  wprep_kernel<<<WP5, 256, 0, stream>>>(wqkv, wqkvT, wo, woT, w1, w1T, w2, w2T,
                                        rel, biasF, x, ln1_g, ln1_b, hbuf);
  // QKV: h @ wqkv + bqkv -> q (pre-scaled), k, Vt (bf16, attention layouts)
  gemm_bt<MODE_QKV><<<dim3(2304 / 128, NTOK / 128), 256, 0, stream>>>(
      hbuf, wqkvT, 768, bqkv, nullptr, nullptr, qbuf, kbuf, vtbuf);
  // attention -> ctx (bf16, [tok][D])
  attn_kernel<<<8 * NH * (SEQ / 128), 256, 0, stream>>>(qbuf, kbuf, vtbuf, biasF, ctxb);
  // proj: ctx @ wo + bo + x -> x2 (fp32, in d_out)
  gemm_bt<MODE_PROJ><<<dim3(768 / 128, NTOK / 128), 256, 0, stream>>>(
      ctxb, woT, 768, bo, x, out, nullptr, nullptr, nullptr);
  // LN2: x2 -> h2 (bf16, reuse hbuf)
  ln_kernel<<<NTOK / 4, 256, 0, stream>>>(out, ln2_g, ln2_b, hbuf);
  // FFN1: h2 @ w1 + b1, gelu -> h1 (bf16)
  gemm_bt<MODE_FFN1><<<dim3(DFF / 128, NTOK / 128), 256, 0, stream>>>(
      hbuf, w1T, 768, b1, nullptr, nullptr, h1buf, nullptr, nullptr);
  // FFN2: h1 @ w2 + b2 + x2 -> out (fp32, in place on d_out)
  gemm_bt<MODE_FFN2><<<dim3(768 / 128, NTOK / 128), 256, 0, stream>>>(
      h1buf, w2T, 3072, b2, out, out, nullptr, nullptr, nullptr);
}